// Round 2
// baseline (145.781 us; speedup 1.0000x reference)
//
#include <hip/hip_runtime.h>

// VQ-VAE VectorQuantizer forward, MI355X (gfx950), fp32.
// N=32768 points x D=64 dims, K=1024 codes.
// Out: [0]=loss, [1..QE]=quantized [B,D,H,W], [+..]=indices [B,H*W] as f32.
//
// R6: LDS-issue attack. R5 was LDS-pipe-bound: 12288 ds_read_b128/block
// (~147K cyc/CU) vs 65.5K cyc VALU floor; occupancy fix alone moved nothing.
// Now: 8x8 per-thread tile (r=32 FMA/LDS-instr), 2 chunks of 512 codes,
// x read straight from global (wave-uniform addr -> 1 L1 transaction,
// 32KB slice stays L1/L2-hot) on the idle VMEM pipe, e from LDS in a
// [d][h][g][q] swizzled row so lanes read contiguous 16B -> conflict-free.
// LDS instrs: 4096/block (~49K cyc) < VALU 65.5K -> VALU-bound.
// xT buffer gone; epilogue reads x from global and stores directly.
// All per-(point,code) fmaf chains, fold exprs, tie-breaks, and the loss
// partition/order are verbatim R4 -> absmax must stay 0.

constexpr int D_   = 64;
constexpr int HW   = 1024;     // H*W
constexpr int K_   = 1024;
constexpr int PTS  = 128;      // points per block
constexpr int CK   = 512;      // codes per chunk (2 chunks)
constexpr int SEC  = 520;      // eTs row stride (floats), 16B-aligned rows
constexpr int QE   = 2097152;
constexpr int IDX_OFF = 1 + QE;

__global__ __launch_bounds__(1024, 4) void vq_main_kernel(
    const float* __restrict__ in, const float* __restrict__ emb,
    float* __restrict__ out, float* __restrict__ loss_acc,
    unsigned* __restrict__ cnt) {
  __shared__ float eTs[D_ * SEC];    // 133.1 KB; row d = [h][g][q] swizzle
  __shared__ float e2s[K_];          // 4 KB
  __shared__ float x2s[PTS];
  __shared__ int   idx_sel[PTS];
  __shared__ float redbuf[8];

  const int t    = threadIdx.x;
  const int lane = t & 63;           // = code group: 8 codes (kg)
  const int wv   = t >> 6;           // wave 0..15 = point group: 8 points
  const int p0   = wv * 8;
  const int blk  = blockIdx.x;
  const int b    = blk >> 3;         // 8 blocks per image
  const int hw0  = (blk & 7) * PTS;
  const float* inb = in + b * (D_ * HW) + hw0;

  // staging role: chunk-local code kl, dim-half h2 (32 dims)
  const int kl = t & 511;
  const int h2 = t >> 9;
  // swizzled position of code kl within a d-row: [h][g][q]
  //   h=(kl>>2)&1 selects 256-float half, g=kl>>3 group, q=kl&3
  const int pos = ((kl >> 2) & 1) * 256 + (kl >> 3) * 4 + (kl & 3);

  // ---- e2s: 1 code/thread, body identical to R4/R5 (rounding!) ----
  {
    const float4* e4 = (const float4*)(emb + t * 64);
    float s = 0.f;
#pragma unroll
    for (int q = 0; q < 16; ++q) {
      float4 v = e4[q];
      s += v.x * v.x; s += v.y * v.y; s += v.z * v.z; s += v.w * v.w;
    }
    e2s[t] = s;
  }

  // ---- stage chunk 0 into swizzled eTs ----
  // write banks: pos covers (4g+q) mod 32 twice (h=0/1) -> 2-way = free
  {
    const float4* g = (const float4*)(emb + kl * 64 + h2 * 32);
    float4 pf[8];
#pragma unroll
    for (int r = 0; r < 8; ++r) pf[r] = g[r];
#pragma unroll
    for (int r = 0; r < 8; ++r) {
      int d = h2 * 32 + r * 4;
      eTs[(d + 0) * SEC + pos] = pf[r].x;
      eTs[(d + 1) * SEC + pos] = pf[r].y;
      eTs[(d + 2) * SEC + pos] = pf[r].z;
      eTs[(d + 3) * SEC + pos] = pf[r].w;
    }
  }

  // ---- x2[p] from global (sequential d fmaf chain — identical values) ----
  if (t < PTS) {
    float s = 0.f;
#pragma unroll 8
    for (int d = 0; d < D_; ++d) { float xv = inb[d * HW + t]; s = fmaf(xv, xv, s); }
    x2s[t] = s;
  }
  __syncthreads();

  float minv[8]; int mini[8];
#pragma unroll
  for (int i = 0; i < 8; ++i) { minv[i] = 3.4e38f; mini[i] = 0; }

  // ---- K loop: 2 chunks of 512 codes ----
#pragma unroll 1
  for (int c = 0; c < 2; ++c) {
    float acc[8][8];
#pragma unroll
    for (int i = 0; i < 8; ++i)
#pragma unroll
      for (int j = 0; j < 8; ++j) acc[i][j] = 0.f;

    const float* xp = inb + p0;          // global, wave-uniform addr
    const float* ep = &eTs[lane * 4];    // lane-contiguous 16B: conflict-free
#pragma unroll 2
    for (int d = 0; d < D_; ++d) {
      float4 xa = *(const float4*)(xp);
      float4 xb = *(const float4*)(xp + 4);
      float4 e0 = *(const float4*)(ep);          // codes lane*8+0..3
      float4 e1 = *(const float4*)(ep + 256);    // codes lane*8+4..7
      xp += HW; ep += SEC;
      float xf[8] = {xa.x, xa.y, xa.z, xa.w, xb.x, xb.y, xb.z, xb.w};
      float ef[8] = {e0.x, e0.y, e0.z, e0.w, e1.x, e1.y, e1.z, e1.w};
#pragma unroll
      for (int i = 0; i < 8; ++i)
#pragma unroll
        for (int j = 0; j < 8; ++j)
          acc[i][j] = fmaf(xf[i], ef[j], acc[i][j]);
    }

    // fold: u = fl(fl(x2 - 2*dot) + e2) — identical expression/order to R4
    float x2v[8];
    {
      float4 xa = *(const float4*)&x2s[p0];      // broadcast
      float4 xb = *(const float4*)&x2s[p0 + 4];
      x2v[0]=xa.x; x2v[1]=xa.y; x2v[2]=xa.z; x2v[3]=xa.w;
      x2v[4]=xb.x; x2v[5]=xb.y; x2v[6]=xb.z; x2v[7]=xb.w;
    }
    float e2f[8];
    {
      const float4* p4 = (const float4*)&e2s[c * CK + lane * 8];
      float4 v0 = p4[0], v1 = p4[1];
      e2f[0]=v0.x; e2f[1]=v0.y; e2f[2]=v0.z; e2f[3]=v0.w;
      e2f[4]=v1.x; e2f[5]=v1.y; e2f[6]=v1.z; e2f[7]=v1.w;
    }
#pragma unroll
    for (int j = 0; j < 8; ++j) {
      int cg = c * CK + lane * 8 + j;            // ascending within thread
      float e2v = e2f[j];
#pragma unroll
      for (int i = 0; i < 8; ++i) {
        float u = fmaf(-2.f, acc[i][j], x2v[i]) + e2v;
        if (u < minv[i]) { minv[i] = u; mini[i] = cg; }
      }
    }

    // stage chunk 1 (no register prefetch across compute: keeps VGPR<=128;
    // one ~0.2us exposed latency, trivial vs 27us compute)
    if (c == 0) {
      __syncthreads();   // all waves done reading eTs chunk 0
      const float4* g = (const float4*)(emb + (CK + kl) * 64 + h2 * 32);
      float4 pf[8];
#pragma unroll
      for (int r = 0; r < 8; ++r) pf[r] = g[r];
#pragma unroll
      for (int r = 0; r < 8; ++r) {
        int d = h2 * 32 + r * 4;
        eTs[(d + 0) * SEC + pos] = pf[r].x;
        eTs[(d + 1) * SEC + pos] = pf[r].y;
        eTs[(d + 2) * SEC + pos] = pf[r].z;
        eTs[(d + 3) * SEC + pos] = pf[r].w;
      }
      __syncthreads();
    }
  }

  // ---- argmin: full-wave butterfly (each wave owns its 8 points) ----
#pragma unroll
  for (int i = 0; i < 8; ++i) {
    float v = minv[i]; int ix = mini[i];
#pragma unroll
    for (int off = 1; off < 64; off <<= 1) {
      float vo = __shfl_xor(v, off);
      int   io = __shfl_xor(ix, off);
      if (vo < v || (vo == v && io < ix)) { v = vo; ix = io; }  // tie -> lower
    }
    if (lane == 0) idx_sel[p0 + i] = ix;
  }
  __syncthreads();

  if (t < PTS) out[IDX_OFF + blk * PTS + t] = (float)idx_sel[t];

  // ---- fused epilogue: gather codes, loss partial, store quantized ----
  // t<512 with R4's EXACT per-thread partition/order -> loss bits identical.
  float* outq = out + 1 + b * (D_ * HW) + hw0;
  float lp = 0.f;
  if (t < 512) {
#pragma unroll
    for (int i = 0; i < 4; ++i) {
      int fi = t + i * 512;               // 0..2047
      int p = fi & 127, qd = fi >> 7;     // p contiguous per wave
      int cidx = idx_sel[p];
      float4 q = *(const float4*)(emb + cidx * 64 + qd * 4);
      float xv0 = inb[(qd * 4 + 0) * HW + p];
      float xv1 = inb[(qd * 4 + 1) * HW + p];
      float xv2 = inb[(qd * 4 + 2) * HW + p];
      float xv3 = inb[(qd * 4 + 3) * HW + p];
      float d0 = q.x - xv0, d1 = q.y - xv1, d2 = q.z - xv2, d3 = q.w - xv3;
      lp = fmaf(d0, d0, lp); lp = fmaf(d1, d1, lp);
      lp = fmaf(d2, d2, lp); lp = fmaf(d3, d3, lp);
      outq[(qd * 4 + 0) * HW + p] = xv0 + d0;
      outq[(qd * 4 + 1) * HW + p] = xv1 + d1;
      outq[(qd * 4 + 2) * HW + p] = xv2 + d2;
      outq[(qd * 4 + 3) * HW + p] = xv3 + d3;
    }

    // loss: wave -> block partials in R4's exact order (waves 0..7)
#pragma unroll
    for (int off = 1; off < 64; off <<= 1) lp += __shfl_xor(lp, off);
    if ((t & 63) == 0) redbuf[t >> 6] = lp;
  }
  __syncthreads();
  if (t == 0) {
    float part = 0.f;
#pragma unroll
    for (int w = 0; w < 8; ++w) part += redbuf[w];
    atomicAdd(loss_acc, part);
    __threadfence();
    unsigned old = atomicAdd(cnt, 1u);
    if (old == 255u) {
      __threadfence();
      float total = atomicAdd(loss_acc, 0.0f);  // coherent read-back
      float m = total * (1.0f / 2097152.0f);
      out[0] = m + 0.25f * m;                   // ref op order
    }
  }
}

extern "C" void kernel_launch(void* const* d_in, const int* in_sizes, int n_in,
                              void* d_out, int out_size, void* d_ws, size_t ws_size,
                              hipStream_t stream) {
  const float* in  = (const float*)d_in[0];
  const float* emb = (const float*)d_in[1];
  float* out = (float*)d_out;
  float* loss_acc = (float*)d_ws;                 // ws[0]
  unsigned* cnt   = (unsigned*)d_ws + 4;          // ws[4]

  hipMemsetAsync(d_ws, 0, 64, stream);            // zero accumulator + counter
  vq_main_kernel<<<256, 1024, 0, stream>>>(in, emb, out, loss_acc, cnt);
}